// Round 5
// baseline (207.806 us; speedup 1.0000x reference)
//
#include <hip/hip_runtime.h>
#include <stdint.h>

// LSTM cell: B=8192, DIN=1024, DOUT=1024, fp32 in/out.
// R5: R2's verified 256x256/BK=64 8-phase structure and 16x16x32 fragment
// pattern (measured 0 LDS conflicts), but 16 waves (4M x 4N, 1024 thr) so
// 4 waves/SIMD: per-wave acc halves to 64 VGPR, read bursts get 2x MLP.
// Stage calendar: B(u):P0,P1  B(v):P2,P3  A(v):P4,P5  A(w):P7x2,
// vmcnt(2) at P3/P7 (counted, never 0 mid-loop).

typedef __attribute__((ext_vector_type(8))) _Float16 half8;
typedef __attribute__((ext_vector_type(4))) _Float16 half4;
typedef __attribute__((ext_vector_type(4))) float f32x4;

__device__ __forceinline__ void gload_lds16(const void* g, void* l) {
  __builtin_amdgcn_global_load_lds(
      (const __attribute__((address_space(1))) void*)g,
      (__attribute__((address_space(3))) void*)l, 16, 0, 0);
}

__device__ __forceinline__ float sigf(float x) { return 1.0f / (1.0f + __expf(-x)); }
__device__ __forceinline__ float tanhf_(float x) { return 1.0f - 2.0f / (__expf(2.0f * x) + 1.0f); }

#define FENCE asm volatile("" ::: "memory")
#define BAR do { FENCE; __builtin_amdgcn_s_barrier(); FENCE; } while (0)
#define WAIT_LGKM0 asm volatile("s_waitcnt lgkmcnt(0)" ::: "memory")

// ---------------- packing kernels ----------------

// Wt[n'][k], n' = (j>>4)*64 + g*16 + (j&15); k<1024 -> Wx_g[k][j], else Wh_g.
__global__ void lstm_pack_w8(const float* __restrict__ Wxi, const float* __restrict__ Whi,
                             const float* __restrict__ Wxf, const float* __restrict__ Whf,
                             const float* __restrict__ Wxg, const float* __restrict__ Whg,
                             const float* __restrict__ Wxo, const float* __restrict__ Who,
                             _Float16* __restrict__ Wt) {
  __shared__ float tile[32][33];
  int nt = blockIdx.x;          // 0..127 : g = nt&3, jt32 = nt>>2
  int kt = blockIdx.y;          // 0..63
  int g = nt & 3, jt32 = nt >> 2;
  const float* Wx[4] = {Wxi, Wxf, Wxg, Wxo};
  const float* Wh[4] = {Whi, Whf, Whg, Who};
  int k0 = kt * 32;
  const float* src = (k0 < 1024) ? (Wx[g] + (size_t)k0 * 1024)
                                 : (Wh[g] + (size_t)(k0 - 1024) * 1024);
  int j0 = jt32 * 32;
  int t = threadIdx.x;
  int cc = t & 31, r0 = t >> 5;
  #pragma unroll
  for (int p = 0; p < 4; ++p) {
    int r = p * 8 + r0;
    tile[r][cc] = src[(size_t)r * 1024 + j0 + cc];
  }
  __syncthreads();
  int jj = t >> 3, kk = (t & 7) * 4;
  int j = j0 + jj;
  int np = ((j >> 4) << 6) + g * 16 + (j & 15);
  half4 v;
  v[0] = (_Float16)tile[kk + 0][jj];
  v[1] = (_Float16)tile[kk + 1][jj];
  v[2] = (_Float16)tile[kk + 2][jj];
  v[3] = (_Float16)tile[kk + 3][jj];
  *(half4*)(Wt + (size_t)np * 2048 + k0 + kk) = v;
}

// Xh[8192][2048] fp16: k<1024 -> x[row][k] else h[row][k-1024]
__global__ void lstm_pack_xh(const float* __restrict__ x, const float* __restrict__ h,
                             _Float16* __restrict__ Xh) {
  size_t t = (size_t)blockIdx.x * 256 + threadIdx.x;
  size_t e = t * 8;
  int row = (int)(e >> 11), k = (int)(e & 2047);
  const float* src = (k < 1024) ? (x + (size_t)row * 1024 + k)
                                : (h + (size_t)row * 1024 + (k - 1024));
  float4 f0 = *(const float4*)src;
  float4 f1 = *(const float4*)(src + 4);
  half8 v;
  v[0] = (_Float16)f0.x; v[1] = (_Float16)f0.y; v[2] = (_Float16)f0.z; v[3] = (_Float16)f0.w;
  v[4] = (_Float16)f1.x; v[5] = (_Float16)f1.y; v[6] = (_Float16)f1.z; v[7] = (_Float16)f1.w;
  *(half8*)(Xh + e) = v;
}

__global__ void lstm_pack_bias8(const float* __restrict__ bxi, const float* __restrict__ bhi,
                                const float* __restrict__ bxf, const float* __restrict__ bhf,
                                const float* __restrict__ bxg, const float* __restrict__ bhg,
                                const float* __restrict__ bxo, const float* __restrict__ bho,
                                float* __restrict__ bias) {
  int t = blockIdx.x * 256 + threadIdx.x;
  if (t >= 4096) return;
  const float* bx[4] = {bxi, bxf, bxg, bxo};
  const float* bh[4] = {bhi, bhf, bhg, bho};
  int q = t >> 4, r = t & 15;
  int g = q & 3, j = (q >> 2) * 16 + r;
  bias[t] = bx[g][j] + bh[g][j];
}

// ---------------- 8-phase fused GEMM, 16 waves ----------------
// BM=256, BN=256(packed), BK=64, 16 waves (4M x 4N), per-wave 64x64 out.
// LDS [2][256][64] fp16 per operand; swizzle phys_slot = slot ^ (row&7)
// (R2's verified 0-conflict pattern).
__global__ __launch_bounds__(1024, 4) void lstm_gemm16(
    const _Float16* __restrict__ Xh, const _Float16* __restrict__ Wt,
    const float* __restrict__ c, const float* __restrict__ bias,
    float* __restrict__ out) {
  __shared__ ushort sA[2][256 * 64];
  __shared__ ushort sB[2][256 * 64];

  int bid = blockIdx.x;                 // 512 blocks
  int xcd = bid & 7, idx = bid >> 3;
  int mt = (xcd >> 1) * 8 + (idx >> 3); // 0..31
  int jt = (xcd & 1) * 8 + (idx & 7);   // 0..15
  int brow0 = mt * 256, bcol0 = jt * 256;

  int tid = threadIdx.x, lane = tid & 63, wave = tid >> 6;   // wave 0..15
  int mw = wave >> 2, wn = wave & 3;
  int l15 = lane & 15, l4 = lane >> 4, l7 = lane & 7, l3 = lane >> 3;
  int bsw = ((l7 ^ l3) << 3);           // pre-swizzled source elem offset

  f32x4 acc[4][4] = {};                 // [m-frag][gate]

  int aoff0 = (mw * 64 + l15) * 64;
  int boff0 = (wn * 64 + l15) * 64;
  int so0 = ((0 + l4) ^ l7) << 3;       // ks=0 phys slot offset (elems)
  int so1 = ((4 + l4) ^ l7) << 3;       // ks=1

  auto stageA = [&](int buf, int t, int s) {
    int rowbase = s * 128 + wave * 8;
    const _Float16* src = Xh + (size_t)(brow0 + rowbase + l3) * 2048 + t * 64 + bsw;
    gload_lds16(src, &sA[buf][rowbase * 64]);
  };
  auto stageB = [&](int buf, int t, int s) {
    int rowbase = s * 128 + wave * 8;
    const _Float16* src = Wt + (size_t)(bcol0 + rowbase + l3) * 2048 + t * 64 + bsw;
    gload_lds16(src, &sB[buf][rowbase * 64]);
  };

#define LDA(mg, BUF) do { _Pragma("unroll") for (int mi = 0; mi < 2; ++mi) { \
    const ushort* p_ = &sA[BUF][aoff0 + ((mg) * 32 + mi * 16) * 64];          \
    af[mi][0] = *(const half8*)(p_ + so0);                                    \
    af[mi][1] = *(const half8*)(p_ + so1); } } while (0)
#define LDB(dst, gg, BUF) do { _Pragma("unroll") for (int g2 = 0; g2 < 2; ++g2) { \
    const ushort* p_ = &sB[BUF][boff0 + ((gg) * 32 + g2 * 16) * 64];              \
    dst[g2][0] = *(const half8*)(p_ + so0);                                       \
    dst[g2][1] = *(const half8*)(p_ + so1); } } while (0)
#define MM(mg, gg, bf) do {                                                   \
    __builtin_amdgcn_s_setprio(1);                                            \
    _Pragma("unroll") for (int mi = 0; mi < 2; ++mi)                          \
    _Pragma("unroll") for (int g2 = 0; g2 < 2; ++g2) {                        \
      f32x4 t_ = acc[(mg) * 2 + mi][(gg) * 2 + g2];                           \
      t_ = __builtin_amdgcn_mfma_f32_16x16x32_f16(af[mi][0], bf[g2][0], t_, 0, 0, 0); \
      t_ = __builtin_amdgcn_mfma_f32_16x16x32_f16(af[mi][1], bf[g2][1], t_, 0, 0, 0); \
      acc[(mg) * 2 + mi][(gg) * 2 + g2] = t_; }                               \
    __builtin_amdgcn_s_setprio(0); } while (0)

  // Prologue: tile0 -> buf0 (A+B), tile1 A -> buf1; wait tile0 (oldest 4).
  stageA(0, 0, 0); stageA(0, 0, 1);
  stageB(0, 0, 0); stageB(0, 0, 1);
  stageA(1, 1, 0); stageA(1, 1, 1);
  asm volatile("s_waitcnt vmcnt(2)" ::: "memory");
  BAR;

  half8 af[2][2], bf01[2][2], bf23[2][2];

#pragma unroll 1
  for (int i = 0; i < 16; ++i) {
    const int u = 2 * i + 1, v = 2 * i + 2, w = 2 * i + 3;
    const bool pf = (i < 15);

    // ---- K-tile in buf0: quadrants (0,0),(0,1),(1,1),(1,0) ----
    // P0
    LDA(0, 0); LDB(bf01, 0, 0);
    stageB(1, u, 0);
    BAR; WAIT_LGKM0;
    MM(0, 0, bf01);
    BAR;
    // P1
    LDB(bf23, 1, 0);
    stageB(1, u, 1);
    BAR; WAIT_LGKM0;
    MM(0, 1, bf23);
    BAR;
    // P2
    LDA(1, 0);
    if (pf) stageB(0, v, 0);
    BAR; WAIT_LGKM0;
    MM(1, 1, bf23);
    BAR;
    // P3  [buf1 must be fully staged after this wait]
    if (pf) stageB(0, v, 1);
    MM(1, 0, bf01);
    if (pf) { asm volatile("s_waitcnt vmcnt(2)" ::: "memory"); }
    else    { asm volatile("s_waitcnt vmcnt(0)" ::: "memory"); }
    BAR;

    // ---- K-tile in buf1 ----
    // P4
    LDA(0, 1); LDB(bf01, 0, 1);
    if (pf) stageA(0, v, 0);
    BAR; WAIT_LGKM0;
    MM(0, 0, bf01);
    BAR;
    // P5
    LDB(bf23, 1, 1);
    if (pf) stageA(0, v, 1);
    BAR; WAIT_LGKM0;
    MM(0, 1, bf23);
    BAR;
    // P6
    LDA(1, 1);
    BAR; WAIT_LGKM0;
    MM(1, 1, bf23);
    BAR;
    // P7  [buf0 must be fully staged after this wait]
    if (pf) { stageA(1, w, 0); stageA(1, w, 1); }
    MM(1, 0, bf01);
    if (pf) { asm volatile("s_waitcnt vmcnt(2)" ::: "memory"); }
    BAR;
  }
#undef LDA
#undef LDB
#undef MM

  // ---- fused LSTM epilogue (4 gates = 4 n-frags of this wave) ----
  int j = jt * 64 + wn * 16 + l15;
  int nbase = bcol0 + wn * 64 + l15;
  float bi  = bias[nbase + 0];
  float bff = bias[nbase + 16];
  float bg  = bias[nbase + 32];
  float bo  = bias[nbase + 48];
  float* hout = out;
  float* cout = out + (size_t)8192 * 1024;
  #pragma unroll
  for (int m = 0; m < 4; ++m) {
    #pragma unroll
    for (int r = 0; r < 4; ++r) {
      int grow = brow0 + mw * 64 + m * 16 + l4 * 4 + r;
      size_t o = (size_t)grow * 1024 + j;
      float zi = acc[m][0][r] + bi;
      float zf = acc[m][1][r] + bff;
      float zg = acc[m][2][r] + bg;
      float zo = acc[m][3][r] + bo;
      float ig = sigf(zi);
      float fg = sigf(zf);
      float gg = tanhf_(zg);
      float og = sigf(zo);
      float cold = c[o];
      float cn = fg * cold + ig * gg;
      hout[o] = og * tanhf_(cn);
      cout[o] = cn;
    }
  }
}

// ---------------- fallback path (round-1, validated) ----------------

__global__ void lstm_pack_w_v1(const float* __restrict__ Wxi, const float* __restrict__ Whi,
                               const float* __restrict__ Wxf, const float* __restrict__ Whf,
                               const float* __restrict__ Wxg, const float* __restrict__ Whg,
                               const float* __restrict__ Wxo, const float* __restrict__ Who,
                               _Float16* __restrict__ Wt) {
  __shared__ float tile[32][33];
  int nt = blockIdx.x;
  int kt = blockIdx.y;
  int g = nt & 3, jt = nt >> 2;
  const float* Wx[4] = {Wxi, Wxf, Wxg, Wxo};
  const float* Wh[4] = {Whi, Whf, Whg, Who};
  int k0 = kt * 32;
  const float* src = (k0 < 1024) ? (Wx[g] + (size_t)k0 * 1024)
                                 : (Wh[g] + (size_t)(k0 - 1024) * 1024);
  int j0 = jt * 32;
  int t = threadIdx.x;
  int cc = t & 31, r0 = t >> 5;
  #pragma unroll
  for (int p = 0; p < 4; ++p) {
    int r = p * 8 + r0;
    tile[r][cc] = src[(size_t)r * 1024 + j0 + cc];
  }
  __syncthreads();
  int jj = t >> 3, kk = (t & 7) * 4;
  half4 v;
  v[0] = (_Float16)tile[kk + 0][jj];
  v[1] = (_Float16)tile[kk + 1][jj];
  v[2] = (_Float16)tile[kk + 2][jj];
  v[3] = (_Float16)tile[kk + 3][jj];
  _Float16* dst = Wt + (size_t)(nt * 32 + jj) * 2048 + k0 + kk;
  *(half4*)dst = v;
}

__global__ void lstm_pack_bias_v1(const float* __restrict__ bxi, const float* __restrict__ bhi,
                                  const float* __restrict__ bxf, const float* __restrict__ bhf,
                                  const float* __restrict__ bxg, const float* __restrict__ bhg,
                                  const float* __restrict__ bxo, const float* __restrict__ bho,
                                  float* __restrict__ bias) {
  int t = blockIdx.x * 256 + threadIdx.x;
  if (t >= 4096) return;
  const float* bx[4] = {bxi, bxf, bxg, bxo};
  const float* bh[4] = {bhi, bhf, bhg, bho};
  int jt = t >> 7, g = (t >> 5) & 3, jj = t & 31;
  int j = jt * 32 + jj;
  bias[t] = bx[g][j] + bh[g][j];
}

__global__ __launch_bounds__(256, 2) void lstm_gemm_v1(
    const float* __restrict__ x, const float* __restrict__ h, const float* __restrict__ c,
    const _Float16* __restrict__ Wt, const float* __restrict__ bias,
    float* __restrict__ out) {
  __shared__ ushort sA[128 * 64];
  __shared__ ushort sB[128 * 64];
  int bid = blockIdx.x;
  int sbid = (bid & 7) * 256 + (bid >> 3);
  int mt = sbid >> 5, jt = sbid & 31;
  int brow0 = mt * 128;
  int tid = threadIdx.x;
  int lane = tid & 63, wave = tid >> 6;
  int wr = wave >> 1, wc = wave & 1;
  f32x4 acc[4][4] = {};
  int ar = tid >> 3;
  int as = tid & 7;
  int l3 = lane >> 3, l7w = lane & 7;
  int bsw = ((l7w ^ l3) << 3);
  int l15 = lane & 15, l4 = lane >> 4, l7 = lane & 7;
  for (int kt = 0; kt < 32; ++kt) {
    int k0 = kt * 64;
    const float* asrc = (k0 < 1024) ? (x + k0) : (h + (k0 - 1024));
    #pragma unroll
    for (int stp = 0; stp < 4; ++stp) {
      int row = stp * 32 + ar;
      const float* p = asrc + (size_t)(brow0 + row) * 1024 + as * 8;
      float4 f0 = *(const float4*)p;
      float4 f1 = *(const float4*)(p + 4);
      half8 hv;
      hv[0] = (_Float16)f0.x; hv[1] = (_Float16)f0.y;
      hv[2] = (_Float16)f0.z; hv[3] = (_Float16)f0.w;
      hv[4] = (_Float16)f1.x; hv[5] = (_Float16)f1.y;
      hv[6] = (_Float16)f1.z; hv[7] = (_Float16)f1.w;
      *(half8*)&sA[row * 64 + ((as ^ (row & 7)) << 3)] = hv;
    }
    #pragma unroll
    for (int ccall = 0; ccall < 4; ++ccall) {
      int rowbase = ccall * 32 + wave * 8;
      int grow = jt * 128 + rowbase + l3;
      const _Float16* src = Wt + (size_t)grow * 2048 + k0 + bsw;
      gload_lds16(src, &sB[rowbase * 64]);
    }
    __syncthreads();
    #pragma unroll
    for (int ks = 0; ks < 2; ++ks) {
      half8 af[4], bfr[4];
      #pragma unroll
      for (int mi = 0; mi < 4; ++mi) {
        int row = wr * 64 + mi * 16 + l15;
        af[mi] = *(const half8*)&sA[row * 64 + (((ks * 4 + l4) ^ l7) << 3)];
      }
      #pragma unroll
      for (int g = 0; g < 4; ++g) {
        int nr = g * 32 + wc * 16 + l15;
        bfr[g] = *(const half8*)&sB[nr * 64 + (((ks * 4 + l4) ^ l7) << 3)];
      }
      #pragma unroll
      for (int mi = 0; mi < 4; ++mi)
        #pragma unroll
        for (int g = 0; g < 4; ++g)
          acc[mi][g] = __builtin_amdgcn_mfma_f32_16x16x32_f16(af[mi], bfr[g], acc[mi][g], 0, 0, 0);
    }
    __syncthreads();
  }
  int j = jt * 32 + wc * 16 + l15;
  int nb = jt * 128 + wc * 16 + l15;
  float bi  = bias[nb + 0];
  float bff = bias[nb + 32];
  float bg  = bias[nb + 64];
  float bo  = bias[nb + 96];
  float* hout = out;
  float* cout = out + (size_t)8192 * 1024;
  #pragma unroll
  for (int mi = 0; mi < 4; ++mi) {
    #pragma unroll
    for (int r = 0; r < 4; ++r) {
      int grow = brow0 + wr * 64 + mi * 16 + l4 * 4 + r;
      size_t idx = (size_t)grow * 1024 + j;
      float zi = acc[mi][0][r] + bi;
      float zf = acc[mi][1][r] + bff;
      float zg = acc[mi][2][r] + bg;
      float zo = acc[mi][3][r] + bo;
      float ig = sigf(zi);
      float fg = sigf(zf);
      float gg = tanhf_(zg);
      float og = sigf(zo);
      float cold = c[idx];
      float cn = fg * cold + ig * gg;
      hout[idx] = og * tanhf_(cn);
      cout[idx] = cn;
    }
  }
}

extern "C" void kernel_launch(void* const* d_in, const int* in_sizes, int n_in,
                              void* d_out, int out_size, void* d_ws, size_t ws_size,
                              hipStream_t stream) {
  const float* x   = (const float*)d_in[0];
  const float* h   = (const float*)d_in[1];
  const float* c   = (const float*)d_in[2];
  const float* Wxi = (const float*)d_in[3];
  const float* Whi = (const float*)d_in[4];
  const float* bxi = (const float*)d_in[5];
  const float* bhi = (const float*)d_in[6];
  const float* Wxf = (const float*)d_in[7];
  const float* Whf = (const float*)d_in[8];
  const float* bxf = (const float*)d_in[9];
  const float* bhf = (const float*)d_in[10];
  const float* Wxg = (const float*)d_in[11];
  const float* Whg = (const float*)d_in[12];
  const float* bxg = (const float*)d_in[13];
  const float* bhg = (const float*)d_in[14];
  const float* Wxo = (const float*)d_in[15];
  const float* Who = (const float*)d_in[16];
  const float* bxo = (const float*)d_in[17];
  const float* bho = (const float*)d_in[18];
  float* out = (float*)d_out;

  const size_t WT_BYTES = (size_t)4096 * 2048 * 2;   // 16 MiB
  const size_t XH_BYTES = (size_t)8192 * 2048 * 2;   // 32 MiB
  const size_t NEED = WT_BYTES + XH_BYTES + 4096 * 4;

  if (ws_size >= NEED) {
    _Float16* Wt = (_Float16*)d_ws;
    _Float16* Xh = (_Float16*)((char*)d_ws + WT_BYTES);
    float* bias  = (float*)((char*)d_ws + WT_BYTES + XH_BYTES);
    lstm_pack_w8<<<dim3(128, 64), 256, 0, stream>>>(Wxi, Whi, Wxf, Whf, Wxg, Whg, Wxo, Who, Wt);
    lstm_pack_xh<<<8192, 256, 0, stream>>>(x, h, Xh);
    lstm_pack_bias8<<<16, 256, 0, stream>>>(bxi, bhi, bxf, bhf, bxg, bhg, bxo, bho, bias);
    lstm_gemm16<<<512, 1024, 0, stream>>>(Xh, Wt, c, bias, out);
  } else {
    _Float16* Wt = (_Float16*)d_ws;
    float* bias  = (float*)((char*)d_ws + WT_BYTES);
    lstm_pack_w_v1<<<dim3(128, 64), 256, 0, stream>>>(Wxi, Whi, Wxf, Whf, Wxg, Whg, Wxo, Who, Wt);
    lstm_pack_bias_v1<<<16, 256, 0, stream>>>(bxi, bhi, bxf, bhf, bxg, bhg, bxo, bho, bias);
    lstm_gemm_v1<<<2048, 256, 0, stream>>>(x, h, c, Wt, bias, out);
  }
}

// Round 6
// 170.161 us; speedup vs baseline: 1.2212x; 1.2212x over previous
//
#include <hip/hip_runtime.h>
#include <stdint.h>

// LSTM cell: B=8192, DIN=1024, DOUT=1024, fp32 in/out.
// R6: 256x256/BK=64, 8 waves (2Mx4N), 16x16x32 f16, R2-verified swizzle,
// FOUR phases per iteration (2 per K-tile), ONE barrier per phase.
// Phase = {ds_reads; stage(4 glds); lgkmcnt(0)+sched_barrier; 32-MFMA; [vmcnt(4)]; BAR}.
// WAR safety: each staged region's last reader drained by that phase's own
// LG0 which precedes its BAR; stage issued only after that BAR.
//   Ph0 stages A->buf1 (buf1-A last read prev Ph3, drained by prev Ph3 LG0)
//   Ph1 stages B->buf0 (buf0-B read Ph0, drained Ph0 LG0)
//   Ph2 stages A->buf0 (buf0-A read Ph0/Ph1, drained Ph1 LG0)
//   Ph3 stages B->buf1 (buf1-B read Ph2, drained Ph2 LG0)
// RAW safety: vmcnt(4)+BAR at Ph1 end publishes buf1 (prevPh3-B + Ph0-A);
// vmcnt(4)+BAR at Ph3 end publishes buf0 (Ph1-B + Ph2-A). Never 0 mid-loop.

typedef __attribute__((ext_vector_type(8))) _Float16 half8;
typedef __attribute__((ext_vector_type(4))) _Float16 half4;
typedef __attribute__((ext_vector_type(4))) float f32x4;

__device__ __forceinline__ void gload_lds16(const void* g, void* l) {
  __builtin_amdgcn_global_load_lds(
      (const __attribute__((address_space(1))) void*)g,
      (__attribute__((address_space(3))) void*)l, 16, 0, 0);
}

__device__ __forceinline__ float sigf(float x) { return 1.0f / (1.0f + __expf(-x)); }
__device__ __forceinline__ float tanhf_(float x) { return 1.0f - 2.0f / (__expf(2.0f * x) + 1.0f); }

#define FENCE asm volatile("" ::: "memory")
#define BAR do { FENCE; __builtin_amdgcn_s_barrier(); FENCE; } while (0)
#define LG0 do { asm volatile("s_waitcnt lgkmcnt(0)" ::: "memory"); \
                 __builtin_amdgcn_sched_barrier(0); } while (0)

// ---------------- packing kernels ----------------

// Wt[n'][k], n' = (j>>4)*64 + g*16 + (j&15); k<1024 -> Wx_g[k][j], else Wh_g.
__global__ void lstm_pack_w8(const float* __restrict__ Wxi, const float* __restrict__ Whi,
                             const float* __restrict__ Wxf, const float* __restrict__ Whf,
                             const float* __restrict__ Wxg, const float* __restrict__ Whg,
                             const float* __restrict__ Wxo, const float* __restrict__ Who,
                             _Float16* __restrict__ Wt) {
  __shared__ float tile[32][33];
  int nt = blockIdx.x;          // 0..127 : g = nt&3, jt32 = nt>>2
  int kt = blockIdx.y;          // 0..63
  int g = nt & 3, jt32 = nt >> 2;
  const float* Wx[4] = {Wxi, Wxf, Wxg, Wxo};
  const float* Wh[4] = {Whi, Whf, Whg, Who};
  int k0 = kt * 32;
  const float* src = (k0 < 1024) ? (Wx[g] + (size_t)k0 * 1024)
                                 : (Wh[g] + (size_t)(k0 - 1024) * 1024);
  int j0 = jt32 * 32;
  int t = threadIdx.x;
  int cc = t & 31, r0 = t >> 5;
  #pragma unroll
  for (int p = 0; p < 4; ++p) {
    int r = p * 8 + r0;
    tile[r][cc] = src[(size_t)r * 1024 + j0 + cc];
  }
  __syncthreads();
  int jj = t >> 3, kk = (t & 7) * 4;
  int j = j0 + jj;
  int np = ((j >> 4) << 6) + g * 16 + (j & 15);
  half4 v;
  v[0] = (_Float16)tile[kk + 0][jj];
  v[1] = (_Float16)tile[kk + 1][jj];
  v[2] = (_Float16)tile[kk + 2][jj];
  v[3] = (_Float16)tile[kk + 3][jj];
  *(half4*)(Wt + (size_t)np * 2048 + k0 + kk) = v;
}

// Xh[8192][2048] fp16: k<1024 -> x[row][k] else h[row][k-1024]
__global__ void lstm_pack_xh(const float* __restrict__ x, const float* __restrict__ h,
                             _Float16* __restrict__ Xh) {
  size_t t = (size_t)blockIdx.x * 256 + threadIdx.x;
  size_t e = t * 8;
  int row = (int)(e >> 11), k = (int)(e & 2047);
  const float* src = (k < 1024) ? (x + (size_t)row * 1024 + k)
                                : (h + (size_t)row * 1024 + (k - 1024));
  float4 f0 = *(const float4*)src;
  float4 f1 = *(const float4*)(src + 4);
  half8 v;
  v[0] = (_Float16)f0.x; v[1] = (_Float16)f0.y; v[2] = (_Float16)f0.z; v[3] = (_Float16)f0.w;
  v[4] = (_Float16)f1.x; v[5] = (_Float16)f1.y; v[6] = (_Float16)f1.z; v[7] = (_Float16)f1.w;
  *(half8*)(Xh + e) = v;
}

__global__ void lstm_pack_bias8(const float* __restrict__ bxi, const float* __restrict__ bhi,
                                const float* __restrict__ bxf, const float* __restrict__ bhf,
                                const float* __restrict__ bxg, const float* __restrict__ bhg,
                                const float* __restrict__ bxo, const float* __restrict__ bho,
                                float* __restrict__ bias) {
  int t = blockIdx.x * 256 + threadIdx.x;
  if (t >= 4096) return;
  const float* bx[4] = {bxi, bxf, bxg, bxo};
  const float* bh[4] = {bhi, bhf, bhg, bho};
  int q = t >> 4, r = t & 15;
  int g = q & 3, j = (q >> 2) * 16 + r;
  bias[t] = bx[g][j] + bh[g][j];
}

// ---------------- 4-phase fused GEMM ----------------
__global__ __launch_bounds__(512, 2) void lstm_gemm4(
    const _Float16* __restrict__ Xh, const _Float16* __restrict__ Wt,
    const float* __restrict__ c, const float* __restrict__ bias,
    float* __restrict__ out) {
  __shared__ ushort sA[2][256 * 64];
  __shared__ ushort sB[2][256 * 64];

  int bid = blockIdx.x;                 // 512 blocks
  int xcd = bid & 7, idx = bid >> 3;
  int mt = (xcd >> 1) * 8 + (idx >> 3); // 0..31
  int jt = (xcd & 1) * 8 + (idx & 7);   // 0..15
  int brow0 = mt * 256, bcol0 = jt * 256;

  int tid = threadIdx.x, lane = tid & 63, wave = tid >> 6;
  int wr = wave >> 2, wc = wave & 3;
  int l15 = lane & 15, l4 = lane >> 4, l7 = lane & 7, l3 = lane >> 3;
  int bsw = ((l7 ^ l3) << 3);           // pre-swizzled source elem offset

  f32x4 acc[8][4] = {};                 // [m-frag 0..7][gate]

  int aoff0 = (wr * 128 + l15) * 64;
  int boff0 = (wc * 64 + l15) * 64;
  int so0 = ((0 + l4) ^ l7) << 3;       // ks=0 phys slot offset (elems)
  int so1 = ((4 + l4) ^ l7) << 3;       // ks=1

  auto stageA = [&](int buf, int t, int s) {
    int rowbase = s * 64 + wave * 8;
    const _Float16* src = Xh + (size_t)(brow0 + rowbase + l3) * 2048 + t * 64 + bsw;
    gload_lds16(src, &sA[buf][rowbase * 64]);
  };
  auto stageB = [&](int buf, int t, int s) {
    int rowbase = s * 64 + wave * 8;
    const _Float16* src = Wt + (size_t)(bcol0 + rowbase + l3) * 2048 + t * 64 + bsw;
    gload_lds16(src, &sB[buf][rowbase * 64]);
  };

#define STA(buf, t) do { stageA(buf, t, 0); stageA(buf, t, 1); \
                         stageA(buf, t, 2); stageA(buf, t, 3); } while (0)
#define STB(buf, t) do { stageB(buf, t, 0); stageB(buf, t, 1); \
                         stageB(buf, t, 2); stageB(buf, t, 3); } while (0)

// A-frags for m-half mh (m-frags mh*4..mh*4+3)
#define LDAH(mh, BUF) do { _Pragma("unroll") for (int mi = 0; mi < 4; ++mi) { \
    const ushort* p_ = &sA[BUF][aoff0 + (((mh) * 4 + mi) * 16) * 64];          \
    af[mi][0] = *(const half8*)(p_ + so0);                                     \
    af[mi][1] = *(const half8*)(p_ + so1); } } while (0)
// all 4 B-frags (gates)
#define LDBA(BUF) do { _Pragma("unroll") for (int nf = 0; nf < 4; ++nf) { \
    const ushort* p_ = &sB[BUF][boff0 + (nf * 16) * 64];                   \
    bf[nf][0] = *(const half8*)(p_ + so0);                                 \
    bf[nf][1] = *(const half8*)(p_ + so1); } } while (0)
// 32-MFMA cluster for m-half mh
#define MMH(mh) do {                                                          \
    __builtin_amdgcn_s_setprio(1);                                            \
    _Pragma("unroll") for (int mi = 0; mi < 4; ++mi)                          \
    _Pragma("unroll") for (int nf = 0; nf < 4; ++nf) {                        \
      f32x4 t_ = acc[(mh) * 4 + mi][nf];                                      \
      t_ = __builtin_amdgcn_mfma_f32_16x16x32_f16(af[mi][0], bf[nf][0], t_, 0, 0, 0); \
      t_ = __builtin_amdgcn_mfma_f32_16x16x32_f16(af[mi][1], bf[nf][1], t_, 0, 0, 0); \
      acc[(mh) * 4 + mi][nf] = t_; }                                          \
    __builtin_amdgcn_s_setprio(0); } while (0)

  // Prologue: tile0 (A+B) -> buf0, tile1 B -> buf1; wait tile0 (drain to 4).
  STA(0, 0); STB(0, 0); STB(1, 1);
  asm volatile("s_waitcnt vmcnt(4)" ::: "memory");
  BAR;

  half8 af[4][2], bf[4][2];

#pragma unroll 1
  for (int i = 0; i < 16; ++i) {
    const int u = 2 * i + 1, v = 2 * i + 2, w = 2 * i + 3;
    const bool pf = (i < 15);

    // Ph0: buf0, m-half 0 (+ all B)
    LDBA(0); LDAH(0, 0);
    STA(1, u);
    LG0; MMH(0);
    BAR;
    // Ph1: buf0, m-half 1; publish buf1 (prevPh3-B + Ph0-A) via vmcnt+BAR
    LDAH(1, 0);
    if (pf) STB(0, v);
    LG0; MMH(1);
    if (pf) { asm volatile("s_waitcnt vmcnt(4)" ::: "memory"); }
    else    { asm volatile("s_waitcnt vmcnt(0)" ::: "memory"); }
    BAR;
    // Ph2: buf1, m-half 0 (+ all B)
    LDBA(1); LDAH(0, 1);
    if (pf) STA(0, v);
    LG0; MMH(0);
    BAR;
    // Ph3: buf1, m-half 1; publish buf0 (Ph1-B + Ph2-A)
    LDAH(1, 1);
    if (pf) STB(1, w);
    LG0; MMH(1);
    if (pf) { asm volatile("s_waitcnt vmcnt(4)" ::: "memory"); }
    BAR;
  }
#undef LDAH
#undef LDBA
#undef MMH
#undef STA
#undef STB

  // ---- fused LSTM epilogue (4 gates = 4 n-frags of this wave) ----
  int j = jt * 64 + wc * 16 + l15;
  int nbase = bcol0 + wc * 64 + l15;
  float bi  = bias[nbase + 0];
  float bff = bias[nbase + 16];
  float bg  = bias[nbase + 32];
  float bo  = bias[nbase + 48];
  float* hout = out;
  float* cout = out + (size_t)8192 * 1024;
  #pragma unroll
  for (int m = 0; m < 8; ++m) {
    #pragma unroll
    for (int r = 0; r < 4; ++r) {
      int grow = brow0 + wr * 128 + m * 16 + l4 * 4 + r;
      size_t o = (size_t)grow * 1024 + j;
      float zi = acc[m][0][r] + bi;
      float zf = acc[m][1][r] + bff;
      float zg = acc[m][2][r] + bg;
      float zo = acc[m][3][r] + bo;
      float ig = sigf(zi);
      float fg = sigf(zf);
      float gg = tanhf_(zg);
      float og = sigf(zo);
      float cold = c[o];
      float cn = fg * cold + ig * gg;
      hout[o] = og * tanhf_(cn);
      cout[o] = cn;
    }
  }
}

// ---------------- fallback path (round-1, validated) ----------------

__global__ void lstm_pack_w_v1(const float* __restrict__ Wxi, const float* __restrict__ Whi,
                               const float* __restrict__ Wxf, const float* __restrict__ Whf,
                               const float* __restrict__ Wxg, const float* __restrict__ Whg,
                               const float* __restrict__ Wxo, const float* __restrict__ Who,
                               _Float16* __restrict__ Wt) {
  __shared__ float tile[32][33];
  int nt = blockIdx.x;
  int kt = blockIdx.y;
  int g = nt & 3, jt = nt >> 2;
  const float* Wx[4] = {Wxi, Wxf, Wxg, Wxo};
  const float* Wh[4] = {Whi, Whf, Whg, Who};
  int k0 = kt * 32;
  const float* src = (k0 < 1024) ? (Wx[g] + (size_t)k0 * 1024)
                                 : (Wh[g] + (size_t)(k0 - 1024) * 1024);
  int j0 = jt * 32;
  int t = threadIdx.x;
  int cc = t & 31, r0 = t >> 5;
  #pragma unroll
  for (int p = 0; p < 4; ++p) {
    int r = p * 8 + r0;
    tile[r][cc] = src[(size_t)r * 1024 + j0 + cc];
  }
  __syncthreads();
  int jj = t >> 3, kk = (t & 7) * 4;
  half4 v;
  v[0] = (_Float16)tile[kk + 0][jj];
  v[1] = (_Float16)tile[kk + 1][jj];
  v[2] = (_Float16)tile[kk + 2][jj];
  v[3] = (_Float16)tile[kk + 3][jj];
  _Float16* dst = Wt + (size_t)(nt * 32 + jj) * 2048 + k0 + kk;
  *(half4*)dst = v;
}

__global__ void lstm_pack_bias_v1(const float* __restrict__ bxi, const float* __restrict__ bhi,
                                  const float* __restrict__ bxf, const float* __restrict__ bhf,
                                  const float* __restrict__ bxg, const float* __restrict__ bhg,
                                  const float* __restrict__ bxo, const float* __restrict__ bho,
                                  float* __restrict__ bias) {
  int t = blockIdx.x * 256 + threadIdx.x;
  if (t >= 4096) return;
  const float* bx[4] = {bxi, bxf, bxg, bxo};
  const float* bh[4] = {bhi, bhf, bhg, bho};
  int jt = t >> 7, g = (t >> 5) & 3, jj = t & 31;
  int j = jt * 32 + jj;
  bias[t] = bx[g][j] + bh[g][j];
}

__global__ __launch_bounds__(256, 2) void lstm_gemm_v1(
    const float* __restrict__ x, const float* __restrict__ h, const float* __restrict__ c,
    const _Float16* __restrict__ Wt, const float* __restrict__ bias,
    float* __restrict__ out) {
  __shared__ ushort sA[128 * 64];
  __shared__ ushort sB[128 * 64];
  int bid = blockIdx.x;
  int sbid = (bid & 7) * 256 + (bid >> 3);
  int mt = sbid >> 5, jt = sbid & 31;
  int brow0 = mt * 128;
  int tid = threadIdx.x;
  int lane = tid & 63, wave = tid >> 6;
  int wr = wave >> 1, wc = wave & 1;
  f32x4 acc[4][4] = {};
  int ar = tid >> 3;
  int as = tid & 7;
  int l3 = lane >> 3, l7w = lane & 7;
  int bsw = ((l7w ^ l3) << 3);
  int l15 = lane & 15, l4 = lane >> 4, l7 = lane & 7;
  for (int kt = 0; kt < 32; ++kt) {
    int k0 = kt * 64;
    const float* asrc = (k0 < 1024) ? (x + k0) : (h + (k0 - 1024));
    #pragma unroll
    for (int stp = 0; stp < 4; ++stp) {
      int row = stp * 32 + ar;
      const float* p = asrc + (size_t)(brow0 + row) * 1024 + as * 8;
      float4 f0 = *(const float4*)p;
      float4 f1 = *(const float4*)(p + 4);
      half8 hv;
      hv[0] = (_Float16)f0.x; hv[1] = (_Float16)f0.y;
      hv[2] = (_Float16)f0.z; hv[3] = (_Float16)f0.w;
      hv[4] = (_Float16)f1.x; hv[5] = (_Float16)f1.y;
      hv[6] = (_Float16)f1.z; hv[7] = (_Float16)f1.w;
      *(half8*)&sA[row * 64 + ((as ^ (row & 7)) << 3)] = hv;
    }
    #pragma unroll
    for (int ccall = 0; ccall < 4; ++ccall) {
      int rowbase = ccall * 32 + wave * 8;
      int grow = jt * 128 + rowbase + l3;
      const _Float16* src = Wt + (size_t)grow * 2048 + k0 + bsw;
      gload_lds16(src, &sB[rowbase * 64]);
    }
    __syncthreads();
    #pragma unroll
    for (int ks = 0; ks < 2; ++ks) {
      half8 af[4], bfr[4];
      #pragma unroll
      for (int mi = 0; mi < 4; ++mi) {
        int row = wr * 64 + mi * 16 + l15;
        af[mi] = *(const half8*)&sA[row * 64 + (((ks * 4 + l4) ^ l7) << 3)];
      }
      #pragma unroll
      for (int g = 0; g < 4; ++g) {
        int nr = g * 32 + wc * 16 + l15;
        bfr[g] = *(const half8*)&sB[nr * 64 + (((ks * 4 + l4) ^ l7) << 3)];
      }
      #pragma unroll
      for (int mi = 0; mi < 4; ++mi)
        #pragma unroll
        for (int g = 0; g < 4; ++g)
          acc[mi][g] = __builtin_amdgcn_mfma_f32_16x16x32_f16(af[mi], bfr[g], acc[mi][g], 0, 0, 0);
    }
    __syncthreads();
  }
  int j = jt * 32 + wc * 16 + l15;
  int nb = jt * 128 + wc * 16 + l15;
  float bi  = bias[nb + 0];
  float bff = bias[nb + 32];
  float bg  = bias[nb + 64];
  float bo  = bias[nb + 96];
  float* hout = out;
  float* cout = out + (size_t)8192 * 1024;
  #pragma unroll
  for (int mi = 0; mi < 4; ++mi) {
    #pragma unroll
    for (int r = 0; r < 4; ++r) {
      int grow = brow0 + wr * 64 + mi * 16 + l4 * 4 + r;
      size_t idx = (size_t)grow * 1024 + j;
      float zi = acc[mi][0][r] + bi;
      float zf = acc[mi][1][r] + bff;
      float zg = acc[mi][2][r] + bg;
      float zo = acc[mi][3][r] + bo;
      float ig = sigf(zi);
      float fg = sigf(zf);
      float gg = tanhf_(zg);
      float og = sigf(zo);
      float cold = c[idx];
      float cn = fg * cold + ig * gg;
      hout[idx] = og * tanhf_(cn);
      cout[idx] = cn;
    }
  }
}

extern "C" void kernel_launch(void* const* d_in, const int* in_sizes, int n_in,
                              void* d_out, int out_size, void* d_ws, size_t ws_size,
                              hipStream_t stream) {
  const float* x   = (const float*)d_in[0];
  const float* h   = (const float*)d_in[1];
  const float* c   = (const float*)d_in[2];
  const float* Wxi = (const float*)d_in[3];
  const float* Whi = (const float*)d_in[4];
  const float* bxi = (const float*)d_in[5];
  const float* bhi = (const float*)d_in[6];
  const float* Wxf = (const float*)d_in[7];
  const float* Whf = (const float*)d_in[8];
  const float* bxf = (const float*)d_in[9];
  const float* bhf = (const float*)d_in[10];
  const float* Wxg = (const float*)d_in[11];
  const float* Whg = (const float*)d_in[12];
  const float* bxg = (const float*)d_in[13];
  const float* bhg = (const float*)d_in[14];
  const float* Wxo = (const float*)d_in[15];
  const float* Who = (const float*)d_in[16];
  const float* bxo = (const float*)d_in[17];
  const float* bho = (const float*)d_in[18];
  float* out = (float*)d_out;

  const size_t WT_BYTES = (size_t)4096 * 2048 * 2;   // 16 MiB
  const size_t XH_BYTES = (size_t)8192 * 2048 * 2;   // 32 MiB
  const size_t NEED = WT_BYTES + XH_BYTES + 4096 * 4;

  if (ws_size >= NEED) {
    _Float16* Wt = (_Float16*)d_ws;
    _Float16* Xh = (_Float16*)((char*)d_ws + WT_BYTES);
    float* bias  = (float*)((char*)d_ws + WT_BYTES + XH_BYTES);
    lstm_pack_w8<<<dim3(128, 64), 256, 0, stream>>>(Wxi, Whi, Wxf, Whf, Wxg, Whg, Wxo, Who, Wt);
    lstm_pack_xh<<<8192, 256, 0, stream>>>(x, h, Xh);
    lstm_pack_bias8<<<16, 256, 0, stream>>>(bxi, bhi, bxf, bhf, bxg, bhg, bxo, bho, bias);
    lstm_gemm4<<<512, 512, 0, stream>>>(Xh, Wt, c, bias, out);
  } else {
    _Float16* Wt = (_Float16*)d_ws;
    float* bias  = (float*)((char*)d_ws + WT_BYTES);
    lstm_pack_w_v1<<<dim3(128, 64), 256, 0, stream>>>(Wxi, Whi, Wxf, Whf, Wxg, Whg, Wxo, Who, Wt);
    lstm_pack_bias_v1<<<16, 256, 0, stream>>>(bxi, bhi, bxf, bhf, bxg, bhg, bxo, bho, bias);
    lstm_gemm_v1<<<2048, 256, 0, stream>>>(x, h, c, Wt, bias, out);
  }
}